// Round 19
// baseline (103.529 us; speedup 1.0000x reference)
//
#include <hip/hip_runtime.h>
#include <hip/hip_bf16.h>

#define NN 50000      // nodes
#define NM 10000      // hyperedges
#define NE 500000     // incidences
#define CAPH 128      // fixed bin capacity per hedge
#define CAPN 32       // fixed bin capacity per node
#define SPCAP 4096    // spill safety list
#define NGH 79        // hedge groups (hd>>7)
#define NGN 98        // node groups (n>>9)
#define CAPA 64       // pass-A per-block-per-group region capacity

// phase1: passA binning || MFMA GEMM || er rows
#define BIN_BLK   240
#define GEMM_TILES ((NN + 63) / 64)          // 782
#define ROWS_BLK  300
#define P1_GRID   (BIN_BLK + GEMM_TILES + ROWS_BLK)

// passBH: hedge groups + Wt2 conversion
#define WT2_BLKS  4
#define PBH_GRID  (NGH + WT2_BLKS)           // 83

// merged gather1 || passB_N
#define G1_BLKS   (NM / 16)                  // 625 (16 hedges per 1024-thr block)
#define G1_GRID   (G1_BLKS + NGN)            // 723

typedef short bf16x8 __attribute__((ext_vector_type(8)));
typedef unsigned short u16x8 __attribute__((ext_vector_type(8)));
typedef float f32x4 __attribute__((ext_vector_type(4)));

// ---------------- workspace layout ----------------
// float-sized slots:
//   vke(bf16 u32x64/row) 3,200,000 @ 0
//   ekv(bf16 u32x64/row)   640,000 @ 3,200,000
//   el 100,000 @3,840,000 | er 20,000 @3,940,000 | el2 20,000 @3,960,000
//   er2 100,000 @3,980,000 | cqe 256 @4,080,000 | cqv 256 @4,080,256
//   Wt 8,192 @4,080,512 | Wt2 4,096 @4,088,704
// ints (base = float offset 4,093,000):
//   cur 60,000 @0 | spc_h @60,000 | spc_n @60,001
//   csrH 640,000 @60,004 | csrN 800,000 @700,004
//   spill_h 8,192 @1,500,004 | spill_n 8,192 @1,508,196
//   regA_H 1,213,440 u32 @1,516,388   (240 x 79 x 64)
//   regA_N 1,505,280 u32 @2,729,828   (240 x 98 x 64)
//   cntA_H 18,960 @4,235,108 | cntA_N 23,520 @4,254,068  (end 4,277,588)
static const size_t OFF_VKE  = 0;
static const size_t OFF_EKV  = 3200000;
static const size_t OFF_EL   = 3840000;
static const size_t OFF_ER   = 3940000;
static const size_t OFF_EL2  = 3960000;
static const size_t OFF_ER2  = 3980000;
static const size_t OFF_CQE  = 4080000;
static const size_t OFF_CQV  = 4080256;
static const size_t OFF_WT   = 4080512;
static const size_t OFF_WT2  = 4088704;
static const size_t OFF_INT  = 4093000;
static const size_t I_CUR    = 0;
static const size_t I_SPCH   = 60000;
static const size_t I_SPCN   = 60001;
static const size_t I_CSRH   = 60004;
static const size_t I_CSRN   = 700004;
static const size_t I_SPH    = 1500004;
static const size_t I_SPN    = 1508196;
static const size_t I_REGH   = 1516388;
static const size_t I_REGN   = 2729828;
static const size_t I_CNTAH  = 4235108;
static const size_t I_CNTAN  = 4254068;

__device__ __forceinline__ unsigned short f2bf(float f) {
    unsigned int u = __float_as_uint(f);
    unsigned int r = (u + 0x7fffu + ((u >> 16) & 1u)) >> 16;   // RNE
    return (unsigned short)r;
}
__device__ __forceinline__ float bflo(unsigned int p) { return __uint_as_float(p << 16); }
__device__ __forceinline__ float bfhi(unsigned int p) { return __uint_as_float(p & 0xffff0000u); }

// ---- prep: zero spill counts; blocks 0,1 = attn folds; 2..65 = Wt ----
__global__ void prep_kernel(const float* __restrict__ W_qe, const float* __restrict__ attn_qe,
                            float* __restrict__ cqe,
                            const float* __restrict__ W_qv, const float* __restrict__ attn_qv,
                            float* __restrict__ cqv,
                            const float* __restrict__ W_ke, unsigned short* __restrict__ Wt,
                            int* __restrict__ spc_h, int* __restrict__ spc_n) {
    int b = blockIdx.x, t = threadIdx.x;     // 66 blocks x 256 threads
    if (b == 0 && t == 0) { *spc_h = 0; *spc_n = 0; }
    if (b < 2) {
        const float* W    = b ? W_qv : W_qe;
        const float* attn = b ? attn_qv : attn_qe;
        float*       c    = b ? cqv : cqe;
        int h = t >> 7, k = t & 127;
        float s = 0.f;
        #pragma unroll 8
        for (int j = 0; j < 64; ++j) s += W[k * 128 + h * 64 + j] * attn[h * 64 + j];
        c[h * 128 + k] = s;
    } else {
        int col = (b - 2) * 2 + (t >> 7), k = t & 127;
        Wt[col * 128 + k] = f2bf(W_ke[k * 128 + col]);
    }
}

// ---- phase1 merged kernel: passA group-binning || MFMA GEMM+el+er2 || er rows ----
struct P1Smem {
    unsigned short Abuf[64 * 128];   // 16 KB
    unsigned short Wbuf[128 * 128];  // 32 KB
};

__global__ __launch_bounds__(256) void phase1_kernel(
        // passA role
        const int* __restrict__ inc_n, const int* __restrict__ inc_h,
        unsigned int* __restrict__ regA_H, unsigned int* __restrict__ regA_N,
        int* __restrict__ cntA_H, int* __restrict__ cntA_N,
        int* __restrict__ spc_h, int2* __restrict__ spill_h,
        int* __restrict__ spc_n, int2* __restrict__ spill_n,
        // gemm role
        const float* __restrict__ X, const unsigned short* __restrict__ Wt,
        const float* __restrict__ attn, const float* __restrict__ cq,
        unsigned short* __restrict__ Y, float* __restrict__ el, float* __restrict__ er2,
        // rows_dot role
        const float* __restrict__ EF, const float* __restrict__ cqe,
        float* __restrict__ er) {
    __shared__ P1Smem sm;
    int bid = blockIdx.x, tid = threadIdx.x;

    if (bid < BIN_BLK) {
        // ===== passA: block-private group binning, LDS cursors (NO fabric atomics);
        // regular stores so L2 write-combines block-private lines =====
        int* cH = (int*)sm.Abuf;          // 79 ints
        int* cN = cH + NGH;               // 98 ints
        for (int i = tid; i < NGH + NGN; i += 256) cH[i] = 0;
        __syncthreads();
        int b = bid;
        for (int t = bid * 256 + tid; t < NE; t += BIN_BLK * 256) {
            int n  = __builtin_nontemporal_load(&inc_n[t]);
            int hd = __builtin_nontemporal_load(&inc_h[t]);
            unsigned int p = (unsigned int)n | ((unsigned int)hd << 16);
            int gh = hd >> 7;
            int sh = atomicAdd(&cH[gh], 1);
            if (sh < CAPA)
                regA_H[((size_t)b * NGH + gh) * CAPA + sh] = p;
            else { int s = atomicAdd(spc_h, 1); if (s < SPCAP) spill_h[s] = make_int2(hd, n); }
            int gn = n >> 9;
            int sn = atomicAdd(&cN[gn], 1);
            if (sn < CAPA)
                regA_N[((size_t)b * NGN + gn) * CAPA + sn] = p;
            else { int s = atomicAdd(spc_n, 1); if (s < SPCAP) spill_n[s] = make_int2(n, hd); }
        }
        __syncthreads();
        for (int i = tid; i < NGH; i += 256) cntA_H[b * NGH + i] = cH[i];
        for (int i = tid; i < NGN; i += 256) cntA_N[b * NGN + i] = cN[i];
        return;
    }
    if (bid >= BIN_BLK + GEMM_TILES) {
        // ================= er rows: er[m][h] = EF[m,:].cqe[h,:] =================
        int wave = tid >> 6, lane = tid & 63;
        for (int g = bid - BIN_BLK - GEMM_TILES; g < (NM + 3) / 4; g += ROWS_BLK) {
            int m = g * 4 + wave;
            if (m < NM) {
                float x0 = EF[(size_t)m * 128 + lane];
                float x1 = EF[(size_t)m * 128 + 64 + lane];
                float a0 = x0 * cqe[lane]       + x1 * cqe[64 + lane];
                float a1 = x0 * cqe[128 + lane] + x1 * cqe[192 + lane];
                for (int off = 32; off > 0; off >>= 1) {
                    a0 += __shfl_down(a0, off);
                    a1 += __shfl_down(a1, off);
                }
                if (lane == 0) { er[m * 2] = a0; er[m * 2 + 1] = a1; }
            }
        }
        return;
    }

    // ================= MFMA GEMM tile =================
    int m0 = (bid - BIN_BLK) * 64;
    const int R = NN;
    // ---- stage W (bf16 global, coalesced) ----
    {
        const u16x8* Wg = reinterpret_cast<const u16x8*>(Wt);
        #pragma unroll
        for (int i = 0; i < 8; ++i) {
            int idx16 = i * 256 + tid;           // 2048 x 16B
            u16x8 w8 = Wg[idx16];
            int col = idx16 >> 4, kb = idx16 & 15;
            int us = (col * 128 + kb * 8) ^ ((col & 7) << 3);
            *reinterpret_cast<u16x8*>(&sm.Wbuf[us]) = w8;
        }
    }
    // ---- stage X (f32 -> bf16) + er2 partial dot with cq ----
    {
        int r = tid >> 2, q = tid & 3;           // 4 threads per row, 32 cols each
        int m = m0 + r;
        float p0 = 0.f, p1 = 0.f;
        if (m < R) {
            const float4* Xr = reinterpret_cast<const float4*>(X + (size_t)m * 128 + q * 32);
            #pragma unroll
            for (int i2 = 0; i2 < 4; ++i2) {
                float4 u = Xr[i2 * 2], v = Xr[i2 * 2 + 1];
                int k0 = q * 32 + i2 * 8;
                u16x8 w8;
                w8[0] = f2bf(u.x); w8[1] = f2bf(u.y); w8[2] = f2bf(u.z); w8[3] = f2bf(u.w);
                w8[4] = f2bf(v.x); w8[5] = f2bf(v.y); w8[6] = f2bf(v.z); w8[7] = f2bf(v.w);
                int us = (r * 128 + k0) ^ ((r & 7) << 3);
                *reinterpret_cast<u16x8*>(&sm.Abuf[us]) = w8;
                p0 += u.x * cq[k0] + u.y * cq[k0 + 1] + u.z * cq[k0 + 2] + u.w * cq[k0 + 3]
                    + v.x * cq[k0 + 4] + v.y * cq[k0 + 5] + v.z * cq[k0 + 6] + v.w * cq[k0 + 7];
                p1 += u.x * cq[128 + k0] + u.y * cq[128 + k0 + 1] + u.z * cq[128 + k0 + 2] + u.w * cq[128 + k0 + 3]
                    + v.x * cq[128 + k0 + 4] + v.y * cq[128 + k0 + 5] + v.z * cq[128 + k0 + 6] + v.w * cq[128 + k0 + 7];
            }
        } else {
            u16x8 z = {0, 0, 0, 0, 0, 0, 0, 0};
            #pragma unroll
            for (int i2 = 0; i2 < 4; ++i2) {
                int us = (r * 128 + q * 32 + i2 * 8) ^ ((r & 7) << 3);
                *reinterpret_cast<u16x8*>(&sm.Abuf[us]) = z;
            }
        }
        p0 += __shfl_xor(p0, 1); p0 += __shfl_xor(p0, 2);
        p1 += __shfl_xor(p1, 1); p1 += __shfl_xor(p1, 2);
        if (q == 0 && m < R)
            reinterpret_cast<float2*>(er2 + (size_t)m * 2)[0] = make_float2(p0, p1);
    }
    __syncthreads();

    // ---- MFMA: wave w -> rows [w*16, w*16+16), 8 col-tiles, 4 K-steps ----
    int l = tid & 63, w = tid >> 6;
    int lrow = w * 16 + (l & 15);
    f32x4 acc[8];
    #pragma unroll
    for (int ct = 0; ct < 8; ++ct) acc[ct] = (f32x4){0.f, 0.f, 0.f, 0.f};
    #pragma unroll
    for (int s = 0; s < 4; ++s) {
        int aidx = (lrow * 128 + s * 32 + (l >> 4) * 8) ^ ((lrow & 7) << 3);
        bf16x8 af = *reinterpret_cast<const bf16x8*>(&sm.Abuf[aidx]);
        #pragma unroll
        for (int ct = 0; ct < 8; ++ct) {
            int col = ct * 16 + (l & 15);
            int bidx = (col * 128 + s * 32 + (l >> 4) * 8) ^ ((col & 7) << 3);
            bf16x8 bf = *reinterpret_cast<const bf16x8*>(&sm.Wbuf[bidx]);
            acc[ct] = __builtin_amdgcn_mfma_f32_16x16x32_bf16(af, bf, acc[ct], 0, 0, 0);
        }
    }

    // ---- epilogue: Y bf16 store, el reduce ----
    float av[8];
    #pragma unroll
    for (int ct = 0; ct < 8; ++ct) av[ct] = attn[ct * 16 + (l & 15)];
    #pragma unroll
    for (int r = 0; r < 4; ++r) {
        int m = m0 + w * 16 + (l >> 4) * 4 + r;
        bool ok = (m < R);
        #pragma unroll
        for (int ct = 0; ct < 8; ++ct)
            if (ok) Y[(size_t)m * 128 + ct * 16 + (l & 15)] = f2bf(acc[ct][r]);
        #pragma unroll
        for (int h = 0; h < 2; ++h) {
            float p = acc[h * 4][r] * av[h * 4] + acc[h * 4 + 1][r] * av[h * 4 + 1]
                    + acc[h * 4 + 2][r] * av[h * 4 + 2] + acc[h * 4 + 3][r] * av[h * 4 + 3];
            p += __shfl_xor(p, 1); p += __shfl_xor(p, 2);
            p += __shfl_xor(p, 4); p += __shfl_xor(p, 8);
            if ((l & 15) == 0 && ok) el[(size_t)m * 2 + h] = p;
        }
    }
}

// ---- passBH: hedge-group re-binning (blocks 0..78) + Wt2 conversion (79..82) ----
__global__ __launch_bounds__(1024) void passBH_kernel(
        const unsigned int* __restrict__ regA_H, const int* __restrict__ cntA_H,
        unsigned short* __restrict__ csrH, int* __restrict__ cur,
        int* __restrict__ spc_h, int2* __restrict__ spill_h,
        const float* __restrict__ W_kv, unsigned int* __restrict__ Wt2) {
    __shared__ int cnt[128];
    __shared__ int ca[BIN_BLK];
    int tid = threadIdx.x;
    if (blockIdx.x >= NGH) {
        int i = (blockIdx.x - NGH) * 1024 + tid;     // 0..4095
        if (i < 4096) {
            int k = i >> 6, l = i & 63;
            unsigned int lo = f2bf(W_kv[k * 128 + 2 * l]);
            unsigned int hi = f2bf(W_kv[k * 128 + 2 * l + 1]);
            Wt2[k * 64 + l] = (hi << 16) | lo;
        }
        return;
    }
    int g = blockIdx.x;
    int w = tid >> 6, lane = tid & 63;    // 16 waves
    for (int i = tid; i < 128; i += 1024) cnt[i] = 0;
    for (int i = tid; i < BIN_BLK; i += 1024) ca[i] = cntA_H[i * NGH + g];
    __syncthreads();
    for (int b = w; b < BIN_BLK; b += 16) {
        int cb = ca[b]; if (cb > CAPA) cb = CAPA;
        if (lane < cb) {
            unsigned int p = regA_H[((size_t)b * NGH + g) * CAPA + lane];
            int n = p & 0xFFFF, hd = p >> 16;
            int slot = atomicAdd(&cnt[hd & 127], 1);
            if (slot < CAPH) csrH[hd * CAPH + slot] = (unsigned short)n;
            else { int s = atomicAdd(spc_h, 1); if (s < SPCAP) spill_h[s] = make_int2(hd, n); }
        }
    }
    __syncthreads();
    for (int i = tid; i < 128; i += 1024) {
        int hd = g * 128 + i;
        if (hd < NM) cur[hd] = cnt[i];
    }
}

// ---- merged: gather1+GEMV (blocks 0..624, 16 hedges each) || passB_N (625..722) ----
__global__ __launch_bounds__(1024) void gather1_kernel(
        const int* __restrict__ cur,
        const unsigned short* __restrict__ csrH,
        const unsigned int* __restrict__ vke32,
        const float* __restrict__ el, const float* __restrict__ er,
        const float* __restrict__ bias_e,
        const int* __restrict__ spc_h, const int2* __restrict__ spill_h,
        float* __restrict__ out_e,
        const unsigned int* __restrict__ Wt2, const float* __restrict__ attn_kv,
        unsigned int* __restrict__ ekv32, float* __restrict__ el2,
        // passB_N role
        const unsigned int* __restrict__ regA_N, const int* __restrict__ cntA_N,
        unsigned short* __restrict__ csrN, int* __restrict__ curN,
        int* __restrict__ spc_n, int2* __restrict__ spill_n) {
    __shared__ int cnt[512];
    __shared__ int ca[BIN_BLK];
    int tid = threadIdx.x;
    int wave = tid >> 6, lane = tid & 63;

    if (blockIdx.x >= G1_BLKS) {
        // ================= passB_N: node-group re-binning =================
        int g = blockIdx.x - G1_BLKS;
        for (int i = tid; i < 512; i += 1024) cnt[i] = 0;
        for (int i = tid; i < BIN_BLK; i += 1024) ca[i] = cntA_N[i * NGN + g];
        __syncthreads();
        for (int b = wave; b < BIN_BLK; b += 16) {
            int cb = ca[b]; if (cb > CAPA) cb = CAPA;
            if (lane < cb) {
                unsigned int p = regA_N[((size_t)b * NGN + g) * CAPA + lane];
                int n = p & 0xFFFF, hd = p >> 16;
                int slot = atomicAdd(&cnt[n & 511], 1);
                if (slot < CAPN) csrN[n * CAPN + slot] = (unsigned short)hd;
                else { int s = atomicAdd(spc_n, 1); if (s < SPCAP) spill_n[s] = make_int2(n, hd); }
            }
        }
        __syncthreads();
        for (int i = tid; i < 512; i += 1024) {
            int nd = g * 512 + i;
            if (nd < NN) curN[nd] = cnt[i];
        }
        return;
    }

    // ================= gather1: wave per hedge (16 per block) =================
    int m = blockIdx.x * 16 + wave;               // < NM (grid exact)
    int h = lane >> 5;
    int c = cur[m]; if (c > CAPH) c = CAPH;
    int beg = m * CAPH, end = beg + c;
    float erv = er[m * 2 + h];
    float acc0 = 0.f, acc1 = 0.f, den = 0.f;
    int i = beg;
    for (; i + 7 < end; i += 8) {
        int vs[8]; unsigned int p[8]; float ex[8];
        #pragma unroll
        for (int j = 0; j < 8; ++j) vs[j] = csrH[i + j];
        #pragma unroll
        for (int j = 0; j < 8; ++j) p[j] = vke32[(size_t)vs[j] * 64 + lane];
        #pragma unroll
        for (int j = 0; j < 8; ++j) ex[j] = __expf(fmaxf(el[vs[j] * 2 + h] + erv, 0.f));
        #pragma unroll
        for (int j = 0; j < 8; ++j) {
            den += ex[j];
            acc0 += ex[j] * bflo(p[j]);
            acc1 += ex[j] * bfhi(p[j]);
        }
    }
    for (; i < end; ++i) {
        int vs = csrH[i];
        unsigned int p = vke32[(size_t)vs * 64 + lane];
        float ex = __expf(fmaxf(el[vs * 2 + h] + erv, 0.f));
        den += ex;
        acc0 += ex * bflo(p);
        acc1 += ex * bfhi(p);
    }
    // spill safety (expected empty)
    int sc = *spc_h; if (sc > SPCAP) sc = SPCAP;
    for (int s = 0; s < sc; ++s) {
        int2 pr = spill_h[s];
        if (pr.x == m) {
            int vs = pr.y;
            unsigned int p = vke32[(size_t)vs * 64 + lane];
            float ex = __expf(fmaxf(el[vs * 2 + h] + erv, 0.f));
            den += ex;
            acc0 += ex * bflo(p);
            acc1 += ex * bfhi(p);
        }
    }
    float inv = (den > 0.f) ? 1.f / den : 0.f;
    acc0 *= inv; acc1 *= inv;
    float b0 = __shfl_down(acc0, 32);
    float b1 = __shfl_down(acc1, 32);
    int e0 = 2 * (lane & 31), e1 = e0 + 1;
    float o0 = 0.5f * (acc0 + b0 + bias_e[e0] + bias_e[64 + e0]);
    float o1 = 0.5f * (acc1 + b1 + bias_e[e1] + bias_e[64 + e1]);
    if (lane < 32)
        reinterpret_cast<float2*>(out_e + (size_t)m * 64)[lane] = make_float2(o0, o1);

    // ---- in-wave GEMV (bf16 weights) ----
    float g0 = 0.f, g1 = 0.f;
    #pragma unroll
    for (int k = 0; k < 64; ++k) {
        float rk = __shfl((k & 1) ? o1 : o0, k >> 1);   // row[k] from lane k/2
        unsigned int wv = Wt2[k * 64 + lane];
        g0 += rk * bflo(wv);
        g1 += rk * bfhi(wv);
    }
    ekv32[(size_t)m * 64 + lane] = ((unsigned int)f2bf(g1) << 16) | (unsigned int)f2bf(g0);
    float p = g0 * attn_kv[2 * lane] + g1 * attn_kv[2 * lane + 1];
    p += __shfl_xor(p, 1); p += __shfl_xor(p, 2); p += __shfl_xor(p, 4);
    p += __shfl_xor(p, 8); p += __shfl_xor(p, 16);
    if ((lane & 31) == 0) el2[m * 2 + (lane >> 5)] = p;
}

// ---- final gather over node bins: wave/dest, 8-way MLP unroll ----
template<int CAP>
__global__ void gather_kernel(const int* __restrict__ cnt, const unsigned short* __restrict__ csr,
                              const unsigned int* __restrict__ src32,  // [*,64] bf16x2
                              const float* __restrict__ el_src,        // [*,2]
                              const float* __restrict__ er_dst,        // [R,2]
                              const float* __restrict__ bias,          // [128]
                              const int* __restrict__ spc, const int2* __restrict__ spill,
                              float* __restrict__ out, int R) {
    int wave = threadIdx.x >> 6, lane = threadIdx.x & 63;
    int m = blockIdx.x * 4 + wave;
    if (m >= R) return;
    int h = lane >> 5;
    int c = cnt[m]; if (c > CAP) c = CAP;
    int beg = m * CAP, end = beg + c;
    float er = er_dst[m * 2 + h];
    float acc0 = 0.f, acc1 = 0.f, den = 0.f;
    int i = beg;
    for (; i + 7 < end; i += 8) {
        int vs[8]; unsigned int p[8]; float ex[8];
        #pragma unroll
        for (int j = 0; j < 8; ++j) vs[j] = csr[i + j];
        #pragma unroll
        for (int j = 0; j < 8; ++j) p[j] = src32[(size_t)vs[j] * 64 + lane];
        #pragma unroll
        for (int j = 0; j < 8; ++j) ex[j] = __expf(fmaxf(el_src[vs[j] * 2 + h] + er, 0.f));
        #pragma unroll
        for (int j = 0; j < 8; ++j) {
            den += ex[j];
            acc0 += ex[j] * bflo(p[j]);
            acc1 += ex[j] * bfhi(p[j]);
        }
    }
    for (; i < end; ++i) {
        int vs = csr[i];
        unsigned int p = src32[(size_t)vs * 64 + lane];
        float ex = __expf(fmaxf(el_src[vs * 2 + h] + er, 0.f));
        den += ex;
        acc0 += ex * bflo(p);
        acc1 += ex * bfhi(p);
    }
    int sc = *spc; if (sc > SPCAP) sc = SPCAP;
    for (int s = 0; s < sc; ++s) {
        int2 pr = spill[s];
        if (pr.x == m) {
            int vs = pr.y;
            unsigned int p = src32[(size_t)vs * 64 + lane];
            float ex = __expf(fmaxf(el_src[vs * 2 + h] + er, 0.f));
            den += ex;
            acc0 += ex * bflo(p);
            acc1 += ex * bfhi(p);
        }
    }
    float inv = (den > 0.f) ? 1.f / den : 0.f;
    acc0 *= inv; acc1 *= inv;
    float b0 = __shfl_down(acc0, 32);
    float b1 = __shfl_down(acc1, 32);
    if (lane < 32) {
        int e0 = 2 * lane, e1 = 2 * lane + 1;
        float o0 = 0.5f * (acc0 + b0 + bias[e0] + bias[64 + e0]);
        float o1 = 0.5f * (acc1 + b1 + bias[e1] + bias[64 + e1]);
        reinterpret_cast<float2*>(out + (size_t)m * 64)[lane] = make_float2(o0, o1);
    }
}

extern "C" void kernel_launch(void* const* d_in, const int* in_sizes, int n_in,
                              void* d_out, int out_size, void* d_ws, size_t ws_size,
                              hipStream_t stream) {
    const float* vfeat   = (const float*)d_in[0];
    const float* efeat   = (const float*)d_in[1];
    const int*   inc_n   = (const int*)d_in[2];
    const int*   inc_h   = (const int*)d_in[3];
    const float* W_ke    = (const float*)d_in[4];
    const float* W_qe    = (const float*)d_in[5];
    const float* attn_ke = (const float*)d_in[6];
    const float* attn_qe = (const float*)d_in[7];
    const float* bias_e  = (const float*)d_in[8];
    const float* W_kv    = (const float*)d_in[9];
    const float* W_qv    = (const float*)d_in[10];
    const float* attn_kv = (const float*)d_in[11];
    const float* attn_qv = (const float*)d_in[12];
    const float* bias_v  = (const float*)d_in[13];

    float* ws = (float*)d_ws;
    unsigned int*   vke = (unsigned int*)(ws + OFF_VKE);
    unsigned int*   ekv = (unsigned int*)(ws + OFF_EKV);
    float* el   = ws + OFF_EL;
    float* er   = ws + OFF_ER;
    float* el2  = ws + OFF_EL2;
    float* er2  = ws + OFF_ER2;
    float* cqe  = ws + OFF_CQE;
    float* cqv  = ws + OFF_CQV;
    unsigned short* Wt  = (unsigned short*)(ws + OFF_WT);
    unsigned int*   Wt2 = (unsigned int*)(ws + OFF_WT2);
    int*   ib      = (int*)(ws + OFF_INT);
    int*   cur     = ib + I_CUR;
    int*   spc_h   = ib + I_SPCH;
    int*   spc_n   = ib + I_SPCN;
    unsigned short* csrH = (unsigned short*)(ib + I_CSRH);
    unsigned short* csrN = (unsigned short*)(ib + I_CSRN);
    int2*  spill_h = (int2*)(ib + I_SPH);
    int2*  spill_n = (int2*)(ib + I_SPN);
    unsigned int* regA_H = (unsigned int*)(ib + I_REGH);
    unsigned int* regA_N = (unsigned int*)(ib + I_REGN);
    int*   cntA_H  = ib + I_CNTAH;
    int*   cntA_N  = ib + I_CNTAN;

    float* out_v = (float*)d_out;                   // [50000, 64]
    float* out_e = (float*)d_out + (size_t)NN * 64; // [10000, 64]

    // ---- prep: zero spill counts + attn folds + Wt ----
    prep_kernel<<<dim3(66), dim3(256), 0, stream>>>(W_qe, attn_qe, cqe, W_qv, attn_qv, cqv,
                                                    W_ke, Wt, spc_h, spc_n);

    // ---- phase1: passA group binning || MFMA GEMM || er rows ----
    phase1_kernel<<<dim3(P1_GRID), dim3(256), 0, stream>>>(
        inc_n, inc_h, regA_H, regA_N, cntA_H, cntA_N,
        spc_h, spill_h, spc_n, spill_n,
        vfeat, Wt, attn_ke, cqv, (unsigned short*)vke, el, er2,
        efeat, cqe, er);

    // ---- passBH: hedge re-binning + Wt2 conversion ----
    passBH_kernel<<<dim3(PBH_GRID), dim3(1024), 0, stream>>>(
        regA_H, cntA_H, csrH, cur, spc_h, spill_h, W_kv, Wt2);

    // ---- merged: gather1 + in-wave GEMV || passB_N ----
    gather1_kernel<<<dim3(G1_GRID), dim3(1024), 0, stream>>>(
        cur, csrH, vke, el, er, bias_e, spc_h, spill_h, out_e,
        Wt2, attn_kv, ekv, el2,
        regA_N, cntA_N, csrN, cur + NM, spc_n, spill_n);

    // ---- final gather: hyperedges -> nodes ----
    gather_kernel<CAPN><<<dim3((NN + 3) / 4), dim3(256), 0, stream>>>(
        cur + NM, csrN, ekv, el2, er2, bias_v, spc_n, spill_n, out_v, NN);
}

// Round 20
// 101.466 us; speedup vs baseline: 1.0203x; 1.0203x over previous
//
#include <hip/hip_runtime.h>
#include <hip/hip_bf16.h>

#define NN 50000      // nodes
#define NM 10000      // hyperedges
#define NE 500000     // incidences
#define CAPH 128      // fixed bin capacity per hedge
#define CAPN 32       // fixed bin capacity per node
#define SPCAP 4096    // spill safety list
#define NGH 79        // hedge groups (hd>>7)
#define NGN 98        // node groups (n>>9)
#define CAPA 64       // pass-A per-block-per-group region capacity

// phase1: passA binning || MFMA GEMM || er rows
#define BIN_BLK   240
#define GEMM_TILES ((NN + 63) / 64)          // 782
#define ROWS_BLK  300
#define P1_GRID   (BIN_BLK + GEMM_TILES + ROWS_BLK)

typedef short bf16x8 __attribute__((ext_vector_type(8)));
typedef unsigned short u16x8 __attribute__((ext_vector_type(8)));
typedef float f32x4 __attribute__((ext_vector_type(4)));

// ---------------- workspace layout ----------------
// float-sized slots:
//   vke(bf16 u32x64/row) 3,200,000 @ 0
//   ekv(bf16 u32x64/row)   640,000 @ 3,200,000
//   el 100,000 @3,840,000 | er 20,000 @3,940,000 | el2 20,000 @3,960,000
//   er2 100,000 @3,980,000 | cqe 256 @4,080,000 | cqv 256 @4,080,256
//   Wt 8,192 @4,080,512 | Wt2 4,096 @4,088,704
// ints (base = float offset 4,093,000):
//   cur 60,000 @0 | spc_h @60,000 | spc_n @60,001
//   csrH 640,000 @60,004 | csrN 800,000 @700,004
//   spill_h 8,192 @1,500,004 | spill_n 8,192 @1,508,196
//   regA_H 1,213,440 u32 @1,516,388   (240 x 79 x 64)
//   regA_N 1,505,280 u32 @2,729,828   (240 x 98 x 64)
//   cntA_H 18,960 @4,235,108 | cntA_N 23,520 @4,254,068  (end 4,277,588)
static const size_t OFF_VKE  = 0;
static const size_t OFF_EKV  = 3200000;
static const size_t OFF_EL   = 3840000;
static const size_t OFF_ER   = 3940000;
static const size_t OFF_EL2  = 3960000;
static const size_t OFF_ER2  = 3980000;
static const size_t OFF_CQE  = 4080000;
static const size_t OFF_CQV  = 4080256;
static const size_t OFF_WT   = 4080512;
static const size_t OFF_WT2  = 4088704;
static const size_t OFF_INT  = 4093000;
static const size_t I_CUR    = 0;
static const size_t I_SPCH   = 60000;
static const size_t I_SPCN   = 60001;
static const size_t I_CSRH   = 60004;
static const size_t I_CSRN   = 700004;
static const size_t I_SPH    = 1500004;
static const size_t I_SPN    = 1508196;
static const size_t I_REGH   = 1516388;
static const size_t I_REGN   = 2729828;
static const size_t I_CNTAH  = 4235108;
static const size_t I_CNTAN  = 4254068;

__device__ __forceinline__ unsigned short f2bf(float f) {
    unsigned int u = __float_as_uint(f);
    unsigned int r = (u + 0x7fffu + ((u >> 16) & 1u)) >> 16;   // RNE
    return (unsigned short)r;
}
__device__ __forceinline__ float bflo(unsigned int p) { return __uint_as_float(p << 16); }
__device__ __forceinline__ float bfhi(unsigned int p) { return __uint_as_float(p & 0xffff0000u); }

// ---- prep: zero spill counts; blocks 0,1 = attn folds; 2..65 = Wt; 66..81 = Wt2 ----
__global__ void prep_kernel(const float* __restrict__ W_qe, const float* __restrict__ attn_qe,
                            float* __restrict__ cqe,
                            const float* __restrict__ W_qv, const float* __restrict__ attn_qv,
                            float* __restrict__ cqv,
                            const float* __restrict__ W_ke, unsigned short* __restrict__ Wt,
                            const float* __restrict__ W_kv, unsigned int* __restrict__ Wt2,
                            int* __restrict__ spc_h, int* __restrict__ spc_n) {
    int b = blockIdx.x, t = threadIdx.x;     // 82 blocks x 256 threads
    if (b == 0 && t == 0) { *spc_h = 0; *spc_n = 0; }
    if (b < 2) {
        const float* W    = b ? W_qv : W_qe;
        const float* attn = b ? attn_qv : attn_qe;
        float*       c    = b ? cqv : cqe;
        int h = t >> 7, k = t & 127;
        float s = 0.f;
        #pragma unroll 8
        for (int j = 0; j < 64; ++j) s += W[k * 128 + h * 64 + j] * attn[h * 64 + j];
        c[h * 128 + k] = s;
    } else if (b < 66) {
        int col = (b - 2) * 2 + (t >> 7), k = t & 127;
        Wt[col * 128 + k] = f2bf(W_ke[k * 128 + col]);
    } else {
        int i = (b - 66) * 256 + t;          // 0..4095
        int k = i >> 6, l = i & 63;
        unsigned int lo = f2bf(W_kv[k * 128 + 2 * l]);
        unsigned int hi = f2bf(W_kv[k * 128 + 2 * l + 1]);
        Wt2[k * 64 + l] = (hi << 16) | lo;
    }
}

// ---- phase1 merged kernel: passA group-binning || MFMA GEMM+el+er2 || er rows ----
struct P1Smem {
    unsigned short Abuf[64 * 128];   // 16 KB
    unsigned short Wbuf[128 * 128];  // 32 KB
};

__global__ __launch_bounds__(256) void phase1_kernel(
        // passA role
        const int* __restrict__ inc_n, const int* __restrict__ inc_h,
        unsigned int* __restrict__ regA_H, unsigned int* __restrict__ regA_N,
        int* __restrict__ cntA_H, int* __restrict__ cntA_N,
        int* __restrict__ spc_h, int2* __restrict__ spill_h,
        int* __restrict__ spc_n, int2* __restrict__ spill_n,
        // gemm role
        const float* __restrict__ X, const unsigned short* __restrict__ Wt,
        const float* __restrict__ attn, const float* __restrict__ cq,
        unsigned short* __restrict__ Y, float* __restrict__ el, float* __restrict__ er2,
        // rows_dot role
        const float* __restrict__ EF, const float* __restrict__ cqe,
        float* __restrict__ er) {
    __shared__ P1Smem sm;
    int bid = blockIdx.x, tid = threadIdx.x;

    if (bid < BIN_BLK) {
        // ===== passA: block-private group binning, LDS cursors (NO fabric atomics);
        // regular stores so L2 write-combines block-private lines =====
        int* cH = (int*)sm.Abuf;          // 79 ints
        int* cN = cH + NGH;               // 98 ints
        for (int i = tid; i < NGH + NGN; i += 256) cH[i] = 0;
        __syncthreads();
        int b = bid;
        for (int t = bid * 256 + tid; t < NE; t += BIN_BLK * 256) {
            int n  = __builtin_nontemporal_load(&inc_n[t]);
            int hd = __builtin_nontemporal_load(&inc_h[t]);
            unsigned int p = (unsigned int)n | ((unsigned int)hd << 16);
            int gh = hd >> 7;
            int sh = atomicAdd(&cH[gh], 1);
            if (sh < CAPA)
                regA_H[((size_t)b * NGH + gh) * CAPA + sh] = p;
            else { int s = atomicAdd(spc_h, 1); if (s < SPCAP) spill_h[s] = make_int2(hd, n); }
            int gn = n >> 9;
            int sn = atomicAdd(&cN[gn], 1);
            if (sn < CAPA)
                regA_N[((size_t)b * NGN + gn) * CAPA + sn] = p;
            else { int s = atomicAdd(spc_n, 1); if (s < SPCAP) spill_n[s] = make_int2(n, hd); }
        }
        __syncthreads();
        for (int i = tid; i < NGH; i += 256) cntA_H[b * NGH + i] = cH[i];
        for (int i = tid; i < NGN; i += 256) cntA_N[b * NGN + i] = cN[i];
        return;
    }
    if (bid >= BIN_BLK + GEMM_TILES) {
        // ================= er rows: er[m][h] = EF[m,:].cqe[h,:] =================
        int wave = tid >> 6, lane = tid & 63;
        for (int g = bid - BIN_BLK - GEMM_TILES; g < (NM + 3) / 4; g += ROWS_BLK) {
            int m = g * 4 + wave;
            if (m < NM) {
                float x0 = EF[(size_t)m * 128 + lane];
                float x1 = EF[(size_t)m * 128 + 64 + lane];
                float a0 = x0 * cqe[lane]       + x1 * cqe[64 + lane];
                float a1 = x0 * cqe[128 + lane] + x1 * cqe[192 + lane];
                for (int off = 32; off > 0; off >>= 1) {
                    a0 += __shfl_down(a0, off);
                    a1 += __shfl_down(a1, off);
                }
                if (lane == 0) { er[m * 2] = a0; er[m * 2 + 1] = a1; }
            }
        }
        return;
    }

    // ================= MFMA GEMM tile =================
    int m0 = (bid - BIN_BLK) * 64;
    const int R = NN;
    // ---- stage W (bf16 global, coalesced) ----
    {
        const u16x8* Wg = reinterpret_cast<const u16x8*>(Wt);
        #pragma unroll
        for (int i = 0; i < 8; ++i) {
            int idx16 = i * 256 + tid;           // 2048 x 16B
            u16x8 w8 = Wg[idx16];
            int col = idx16 >> 4, kb = idx16 & 15;
            int us = (col * 128 + kb * 8) ^ ((col & 7) << 3);
            *reinterpret_cast<u16x8*>(&sm.Wbuf[us]) = w8;
        }
    }
    // ---- stage X (f32 -> bf16) + er2 partial dot with cq ----
    {
        int r = tid >> 2, q = tid & 3;           // 4 threads per row, 32 cols each
        int m = m0 + r;
        float p0 = 0.f, p1 = 0.f;
        if (m < R) {
            const float4* Xr = reinterpret_cast<const float4*>(X + (size_t)m * 128 + q * 32);
            #pragma unroll
            for (int i2 = 0; i2 < 4; ++i2) {
                float4 u = Xr[i2 * 2], v = Xr[i2 * 2 + 1];
                int k0 = q * 32 + i2 * 8;
                u16x8 w8;
                w8[0] = f2bf(u.x); w8[1] = f2bf(u.y); w8[2] = f2bf(u.z); w8[3] = f2bf(u.w);
                w8[4] = f2bf(v.x); w8[5] = f2bf(v.y); w8[6] = f2bf(v.z); w8[7] = f2bf(v.w);
                int us = (r * 128 + k0) ^ ((r & 7) << 3);
                *reinterpret_cast<u16x8*>(&sm.Abuf[us]) = w8;
                p0 += u.x * cq[k0] + u.y * cq[k0 + 1] + u.z * cq[k0 + 2] + u.w * cq[k0 + 3]
                    + v.x * cq[k0 + 4] + v.y * cq[k0 + 5] + v.z * cq[k0 + 6] + v.w * cq[k0 + 7];
                p1 += u.x * cq[128 + k0] + u.y * cq[128 + k0 + 1] + u.z * cq[128 + k0 + 2] + u.w * cq[128 + k0 + 3]
                    + v.x * cq[128 + k0 + 4] + v.y * cq[128 + k0 + 5] + v.z * cq[128 + k0 + 6] + v.w * cq[128 + k0 + 7];
            }
        } else {
            u16x8 z = {0, 0, 0, 0, 0, 0, 0, 0};
            #pragma unroll
            for (int i2 = 0; i2 < 4; ++i2) {
                int us = (r * 128 + q * 32 + i2 * 8) ^ ((r & 7) << 3);
                *reinterpret_cast<u16x8*>(&sm.Abuf[us]) = z;
            }
        }
        p0 += __shfl_xor(p0, 1); p0 += __shfl_xor(p0, 2);
        p1 += __shfl_xor(p1, 1); p1 += __shfl_xor(p1, 2);
        if (q == 0 && m < R)
            reinterpret_cast<float2*>(er2 + (size_t)m * 2)[0] = make_float2(p0, p1);
    }
    __syncthreads();

    // ---- MFMA: wave w -> rows [w*16, w*16+16), 8 col-tiles, 4 K-steps ----
    int l = tid & 63, w = tid >> 6;
    int lrow = w * 16 + (l & 15);
    f32x4 acc[8];
    #pragma unroll
    for (int ct = 0; ct < 8; ++ct) acc[ct] = (f32x4){0.f, 0.f, 0.f, 0.f};
    #pragma unroll
    for (int s = 0; s < 4; ++s) {
        int aidx = (lrow * 128 + s * 32 + (l >> 4) * 8) ^ ((lrow & 7) << 3);
        bf16x8 af = *reinterpret_cast<const bf16x8*>(&sm.Abuf[aidx]);
        #pragma unroll
        for (int ct = 0; ct < 8; ++ct) {
            int col = ct * 16 + (l & 15);
            int bidx = (col * 128 + s * 32 + (l >> 4) * 8) ^ ((col & 7) << 3);
            bf16x8 bf = *reinterpret_cast<const bf16x8*>(&sm.Wbuf[bidx]);
            acc[ct] = __builtin_amdgcn_mfma_f32_16x16x32_bf16(af, bf, acc[ct], 0, 0, 0);
        }
    }

    // ---- epilogue: Y bf16 store, el reduce ----
    float av[8];
    #pragma unroll
    for (int ct = 0; ct < 8; ++ct) av[ct] = attn[ct * 16 + (l & 15)];
    #pragma unroll
    for (int r = 0; r < 4; ++r) {
        int m = m0 + w * 16 + (l >> 4) * 4 + r;
        bool ok = (m < R);
        #pragma unroll
        for (int ct = 0; ct < 8; ++ct)
            if (ok) Y[(size_t)m * 128 + ct * 16 + (l & 15)] = f2bf(acc[ct][r]);
        #pragma unroll
        for (int h = 0; h < 2; ++h) {
            float p = acc[h * 4][r] * av[h * 4] + acc[h * 4 + 1][r] * av[h * 4 + 1]
                    + acc[h * 4 + 2][r] * av[h * 4 + 2] + acc[h * 4 + 3][r] * av[h * 4 + 3];
            p += __shfl_xor(p, 1); p += __shfl_xor(p, 2);
            p += __shfl_xor(p, 4); p += __shfl_xor(p, 8);
            if ((l & 15) == 0 && ok) el[(size_t)m * 2 + h] = p;
        }
    }
}

// ---- passB: per-group re-binning into csrH/csrN; one block per group ----
__global__ __launch_bounds__(1024) void passB_kernel(
        const unsigned int* __restrict__ regA_H, const unsigned int* __restrict__ regA_N,
        const int* __restrict__ cntA_H, const int* __restrict__ cntA_N,
        unsigned short* __restrict__ csrH, unsigned short* __restrict__ csrN,
        int* __restrict__ cur,
        int* __restrict__ spc_h, int2* __restrict__ spill_h,
        int* __restrict__ spc_n, int2* __restrict__ spill_n) {
    __shared__ int cnt[512];
    __shared__ int ca[BIN_BLK];
    int tid = threadIdx.x;
    int w = tid >> 6, lane = tid & 63;    // 16 waves

    if (blockIdx.x < NGH) {
        int g = blockIdx.x;
        for (int i = tid; i < 128; i += 1024) cnt[i] = 0;
        for (int i = tid; i < BIN_BLK; i += 1024) ca[i] = cntA_H[i * NGH + g];
        __syncthreads();
        for (int b = w; b < BIN_BLK; b += 16) {
            int cb = ca[b]; if (cb > CAPA) cb = CAPA;
            if (lane < cb) {
                unsigned int p = regA_H[((size_t)b * NGH + g) * CAPA + lane];
                int n = p & 0xFFFF, hd = p >> 16;
                int slot = atomicAdd(&cnt[hd & 127], 1);
                if (slot < CAPH) csrH[hd * CAPH + slot] = (unsigned short)n;
                else { int s = atomicAdd(spc_h, 1); if (s < SPCAP) spill_h[s] = make_int2(hd, n); }
            }
        }
        __syncthreads();
        for (int i = tid; i < 128; i += 1024) {
            int hd = g * 128 + i;
            if (hd < NM) cur[hd] = cnt[i];
        }
    } else {
        int g = blockIdx.x - NGH;
        for (int i = tid; i < 512; i += 1024) cnt[i] = 0;
        for (int i = tid; i < BIN_BLK; i += 1024) ca[i] = cntA_N[i * NGN + g];
        __syncthreads();
        for (int b = w; b < BIN_BLK; b += 16) {
            int cb = ca[b]; if (cb > CAPA) cb = CAPA;
            if (lane < cb) {
                unsigned int p = regA_N[((size_t)b * NGN + g) * CAPA + lane];
                int n = p & 0xFFFF, hd = p >> 16;
                int slot = atomicAdd(&cnt[n & 511], 1);
                if (slot < CAPN) csrN[n * CAPN + slot] = (unsigned short)hd;
                else { int s = atomicAdd(spc_n, 1); if (s < SPCAP) spill_n[s] = make_int2(n, hd); }
            }
        }
        __syncthreads();
        for (int i = tid; i < 512; i += 1024) {
            int nd = g * 512 + i;
            if (nd < NN) cur[NM + nd] = cnt[i];
        }
    }
}

// ---- gather1 + in-wave GEMV (ekv, el2): one wave per hedge, 8-way unroll ----
__global__ __launch_bounds__(256) void gather1_kernel(
        const int* __restrict__ cur,
        const unsigned short* __restrict__ csrH,
        const unsigned int* __restrict__ vke32,
        const float* __restrict__ el, const float* __restrict__ er,
        const float* __restrict__ bias_e,
        const int* __restrict__ spc_h, const int2* __restrict__ spill_h,
        float* __restrict__ out_e,
        const unsigned int* __restrict__ Wt2, const float* __restrict__ attn_kv,
        unsigned int* __restrict__ ekv32, float* __restrict__ el2) {
    int tid = threadIdx.x;
    int wave = tid >> 6, lane = tid & 63;
    int m = blockIdx.x * 4 + wave;                // < NM (grid exact)
    int h = lane >> 5;
    int c = cur[m]; if (c > CAPH) c = CAPH;
    int beg = m * CAPH, end = beg + c;
    float erv = er[m * 2 + h];
    float acc0 = 0.f, acc1 = 0.f, den = 0.f;
    int i = beg;
    for (; i + 7 < end; i += 8) {
        int vs[8]; unsigned int p[8]; float ex[8];
        #pragma unroll
        for (int j = 0; j < 8; ++j) vs[j] = csrH[i + j];
        #pragma unroll
        for (int j = 0; j < 8; ++j) p[j] = vke32[(size_t)vs[j] * 64 + lane];
        #pragma unroll
        for (int j = 0; j < 8; ++j) ex[j] = __expf(fmaxf(el[vs[j] * 2 + h] + erv, 0.f));
        #pragma unroll
        for (int j = 0; j < 8; ++j) {
            den += ex[j];
            acc0 += ex[j] * bflo(p[j]);
            acc1 += ex[j] * bfhi(p[j]);
        }
    }
    for (; i < end; ++i) {
        int vs = csrH[i];
        unsigned int p = vke32[(size_t)vs * 64 + lane];
        float ex = __expf(fmaxf(el[vs * 2 + h] + erv, 0.f));
        den += ex;
        acc0 += ex * bflo(p);
        acc1 += ex * bfhi(p);
    }
    // spill safety (expected empty)
    int sc = *spc_h; if (sc > SPCAP) sc = SPCAP;
    for (int s = 0; s < sc; ++s) {
        int2 pr = spill_h[s];
        if (pr.x == m) {
            int vs = pr.y;
            unsigned int p = vke32[(size_t)vs * 64 + lane];
            float ex = __expf(fmaxf(el[vs * 2 + h] + erv, 0.f));
            den += ex;
            acc0 += ex * bflo(p);
            acc1 += ex * bfhi(p);
        }
    }
    float inv = (den > 0.f) ? 1.f / den : 0.f;
    acc0 *= inv; acc1 *= inv;
    float b0 = __shfl_down(acc0, 32);
    float b1 = __shfl_down(acc1, 32);
    int e0 = 2 * (lane & 31), e1 = e0 + 1;
    float o0 = 0.5f * (acc0 + b0 + bias_e[e0] + bias_e[64 + e0]);
    float o1 = 0.5f * (acc1 + b1 + bias_e[e1] + bias_e[64 + e1]);
    if (lane < 32)
        reinterpret_cast<float2*>(out_e + (size_t)m * 64)[lane] = make_float2(o0, o1);

    // ---- in-wave GEMV (bf16 weights) ----
    float g0 = 0.f, g1 = 0.f;
    #pragma unroll
    for (int k = 0; k < 64; ++k) {
        float rk = __shfl((k & 1) ? o1 : o0, k >> 1);   // row[k] from lane k/2
        unsigned int wv = Wt2[k * 64 + lane];
        g0 += rk * bflo(wv);
        g1 += rk * bfhi(wv);
    }
    ekv32[(size_t)m * 64 + lane] = ((unsigned int)f2bf(g1) << 16) | (unsigned int)f2bf(g0);
    float p = g0 * attn_kv[2 * lane] + g1 * attn_kv[2 * lane + 1];
    p += __shfl_xor(p, 1); p += __shfl_xor(p, 2); p += __shfl_xor(p, 4);
    p += __shfl_xor(p, 8); p += __shfl_xor(p, 16);
    if ((lane & 31) == 0) el2[m * 2 + (lane >> 5)] = p;
}

// ---- final gather over node bins: wave/dest, 8-way MLP unroll ----
template<int CAP>
__global__ void gather_kernel(const int* __restrict__ cnt, const unsigned short* __restrict__ csr,
                              const unsigned int* __restrict__ src32,  // [*,64] bf16x2
                              const float* __restrict__ el_src,        // [*,2]
                              const float* __restrict__ er_dst,        // [R,2]
                              const float* __restrict__ bias,          // [128]
                              const int* __restrict__ spc, const int2* __restrict__ spill,
                              float* __restrict__ out, int R) {
    int wave = threadIdx.x >> 6, lane = threadIdx.x & 63;
    int m = blockIdx.x * 4 + wave;
    if (m >= R) return;
    int h = lane >> 5;
    int c = cnt[m]; if (c > CAP) c = CAP;
    int beg = m * CAP, end = beg + c;
    float er = er_dst[m * 2 + h];
    float acc0 = 0.f, acc1 = 0.f, den = 0.f;
    int i = beg;
    for (; i + 7 < end; i += 8) {
        int vs[8]; unsigned int p[8]; float ex[8];
        #pragma unroll
        for (int j = 0; j < 8; ++j) vs[j] = csr[i + j];
        #pragma unroll
        for (int j = 0; j < 8; ++j) p[j] = src32[(size_t)vs[j] * 64 + lane];
        #pragma unroll
        for (int j = 0; j < 8; ++j) ex[j] = __expf(fmaxf(el_src[vs[j] * 2 + h] + er, 0.f));
        #pragma unroll
        for (int j = 0; j < 8; ++j) {
            den += ex[j];
            acc0 += ex[j] * bflo(p[j]);
            acc1 += ex[j] * bfhi(p[j]);
        }
    }
    for (; i < end; ++i) {
        int vs = csr[i];
        unsigned int p = src32[(size_t)vs * 64 + lane];
        float ex = __expf(fmaxf(el_src[vs * 2 + h] + er, 0.f));
        den += ex;
        acc0 += ex * bflo(p);
        acc1 += ex * bfhi(p);
    }
    int sc = *spc; if (sc > SPCAP) sc = SPCAP;
    for (int s = 0; s < sc; ++s) {
        int2 pr = spill[s];
        if (pr.x == m) {
            int vs = pr.y;
            unsigned int p = src32[(size_t)vs * 64 + lane];
            float ex = __expf(fmaxf(el_src[vs * 2 + h] + er, 0.f));
            den += ex;
            acc0 += ex * bflo(p);
            acc1 += ex * bfhi(p);
        }
    }
    float inv = (den > 0.f) ? 1.f / den : 0.f;
    acc0 *= inv; acc1 *= inv;
    float b0 = __shfl_down(acc0, 32);
    float b1 = __shfl_down(acc1, 32);
    if (lane < 32) {
        int e0 = 2 * lane, e1 = 2 * lane + 1;
        float o0 = 0.5f * (acc0 + b0 + bias[e0] + bias[64 + e0]);
        float o1 = 0.5f * (acc1 + b1 + bias[e1] + bias[64 + e1]);
        reinterpret_cast<float2*>(out + (size_t)m * 64)[lane] = make_float2(o0, o1);
    }
}

extern "C" void kernel_launch(void* const* d_in, const int* in_sizes, int n_in,
                              void* d_out, int out_size, void* d_ws, size_t ws_size,
                              hipStream_t stream) {
    const float* vfeat   = (const float*)d_in[0];
    const float* efeat   = (const float*)d_in[1];
    const int*   inc_n   = (const int*)d_in[2];
    const int*   inc_h   = (const int*)d_in[3];
    const float* W_ke    = (const float*)d_in[4];
    const float* W_qe    = (const float*)d_in[5];
    const float* attn_ke = (const float*)d_in[6];
    const float* attn_qe = (const float*)d_in[7];
    const float* bias_e  = (const float*)d_in[8];
    const float* W_kv    = (const float*)d_in[9];
    const float* W_qv    = (const float*)d_in[10];
    const float* attn_kv = (const float*)d_in[11];
    const float* attn_qv = (const float*)d_in[12];
    const float* bias_v  = (const float*)d_in[13];

    float* ws = (float*)d_ws;
    unsigned int*   vke = (unsigned int*)(ws + OFF_VKE);
    unsigned int*   ekv = (unsigned int*)(ws + OFF_EKV);
    float* el   = ws + OFF_EL;
    float* er   = ws + OFF_ER;
    float* el2  = ws + OFF_EL2;
    float* er2  = ws + OFF_ER2;
    float* cqe  = ws + OFF_CQE;
    float* cqv  = ws + OFF_CQV;
    unsigned short* Wt  = (unsigned short*)(ws + OFF_WT);
    unsigned int*   Wt2 = (unsigned int*)(ws + OFF_WT2);
    int*   ib      = (int*)(ws + OFF_INT);
    int*   cur     = ib + I_CUR;
    int*   spc_h   = ib + I_SPCH;
    int*   spc_n   = ib + I_SPCN;
    unsigned short* csrH = (unsigned short*)(ib + I_CSRH);
    unsigned short* csrN = (unsigned short*)(ib + I_CSRN);
    int2*  spill_h = (int2*)(ib + I_SPH);
    int2*  spill_n = (int2*)(ib + I_SPN);
    unsigned int* regA_H = (unsigned int*)(ib + I_REGH);
    unsigned int* regA_N = (unsigned int*)(ib + I_REGN);
    int*   cntA_H  = ib + I_CNTAH;
    int*   cntA_N  = ib + I_CNTAN;

    float* out_v = (float*)d_out;                   // [50000, 64]
    float* out_e = (float*)d_out + (size_t)NN * 64; // [10000, 64]

    // ---- prep: zero spill counts + attn folds + W transposes ----
    prep_kernel<<<dim3(82), dim3(256), 0, stream>>>(W_qe, attn_qe, cqe, W_qv, attn_qv, cqv,
                                                    W_ke, Wt, W_kv, Wt2, spc_h, spc_n);

    // ---- phase1: passA group binning || MFMA GEMM || er rows ----
    phase1_kernel<<<dim3(P1_GRID), dim3(256), 0, stream>>>(
        inc_n, inc_h, regA_H, regA_N, cntA_H, cntA_N,
        spc_h, spill_h, spc_n, spill_n,
        vfeat, Wt, attn_ke, cqv, (unsigned short*)vke, el, er2,
        efeat, cqe, er);

    // ---- passB: group re-binning -> csrH/csrN + cur ----
    passB_kernel<<<dim3(NGH + NGN), dim3(1024), 0, stream>>>(
        regA_H, regA_N, cntA_H, cntA_N, csrH, csrN, cur,
        spc_h, spill_h, spc_n, spill_n);

    // ---- gather1 + in-wave GEMV ----
    gather1_kernel<<<dim3(NM / 4), dim3(256), 0, stream>>>(
        cur, csrH, vke, el, er, bias_e, spc_h, spill_h, out_e,
        Wt2, attn_kv, ekv, el2);

    // ---- final gather: hyperedges -> nodes ----
    gather_kernel<CAPN><<<dim3((NN + 3) / 4), dim3(256), 0, stream>>>(
        cur + NM, csrN, ekv, el2, er2, bias_v, spc_n, spill_n, out_v, NN);
}